// Round 6
// baseline (66.588 us; speedup 1.0000x reference)
//
#include <hip/hip_runtime.h>

// OTAM cumulative-distance matching, fused forward+transposed DP, one pass.
// similarity: [2048, 128, 16, 16] f32 ; out: [2048, 128] f32
//
// v6: reg-staged global->LDS (compiler-tracked waits, provably race-free),
// depth-1 register prefetch: chunk k+1's loads are issued before chunk k's
// ds_write/compute, so the compiler emits counted s_waitcnt vmcnt(4) and the
// wave always has 4 loads in flight during compute. Chunk = 1 row x 64 pairs
// (4 KB). Wave-private LDS, no barriers (same-wave DS ops are in-order, so
// the single buffer is WAR-safe). XOR swizzle conflict-free for b128 on both
// write and read.

#define K2   14.4269504088896340736f   // 1/(lambda*ln2), lambda = 0.1
#define LL2  0.069314718055994530942f  // lambda*ln(2)

// softmin(a,b) = min - L*ln2*log2(1 + exp2(-|a-b|/(L*ln2)))
__device__ __forceinline__ float softmin2(float a, float b) {
    float mn = fminf(a, b);
    float t  = __builtin_amdgcn_exp2f(-K2 * fabsf(a - b));
    return mn - LL2 * __builtin_amdgcn_logf(1.0f + t);   // logf = v_log_f32 = log2
}

__device__ __forceinline__ float softmin3(float a, float b, float c) {
    float mn = fminf(fminf(a, b), c);   // v_min3_f32
    float s = __builtin_amdgcn_exp2f(-K2 * (a - mn))
            + __builtin_amdgcn_exp2f(-K2 * (b - mn))
            + __builtin_amdgcn_exp2f(-K2 * (c - mn));
    return mn - LL2 * __builtin_amdgcn_logf(s);
}

// DP1 (row-major over D): one row step, in-place with diagonal carry.
__device__ __forceinline__ void dp_row(float* R, const float* dr) {
    float diag = R[0];              // cum1[r-1, 0] = 0
    float oldR = R[1];
    R[1] = dr[0] + softmin3(diag, R[0], oldR);   // m = 1 boundary
    diag = oldR;
#pragma unroll
    for (int m = 2; m <= 16; ++m) {
        float o = R[m];
        R[m] = dr[m - 1] + softmin2(diag, R[m - 1]);
        diag = o;
    }
    R[17] = softmin3(diag, R[16], R[17]);        // m = 17 pad, d = 0, boundary
}

// DP2 (the DP on D^T, advanced column-major): one interior column step.
__device__ __forceinline__ void dp_col(float* C, const float* dr) {
    float diag2 = C[0];             // cum2[0, m-1]
    C[0] = C[0] + dr[0];            // row 0 of DP2 is a plain cumsum
#pragma unroll
    for (int l = 1; l < 16; ++l) {
        float o = C[l];
        C[l] = dr[l] + softmin2(diag2, o);
        diag2 = o;
    }
}

// LDS layout per wave-chunk (1 row x 64 pairs = 1024 floats = 256 b128 slots):
//   float4 #f of pair p  ->  slot  p*4 + (f ^ ((p>>1)&3))
// Write: lane t, instr i stages f=(t&3) of p=i*16+(t>>2):
//   slot = i*64 + (t>>2)*4 + ((t&3) ^ ((t>>3)&3))
//   8 consecutive lanes cover 8 distinct 16B bank-groups (enumerated). 
// Read: lane t, float4 j of its own pair p=t:
//   slot = t*4 + (j ^ ((t>>1)&3))  -> also 8 distinct groups per 8 lanes.

__global__ __launch_bounds__(256, 2)
void otam_fused_kernel(const float* __restrict__ sim, float* __restrict__ out) {
    const int t  = threadIdx.x & 63;
    const int wv = threadIdx.x >> 6;
    const int pair0 = blockIdx.x * 256 + wv * 64;

    __shared__ float lds_all[4 * 1024];              // 16 KB: 4 waves x 4 KB
    float* lds = lds_all + (wv << 10);               // wave-private

    const int u = t >> 2;                            // 0..15: pair sub-index
    const int q = t & 3;                             // 0..3 : float4 within row
    // lane t stages float4 q of pair (pair0 + u + i*16), row r:
    //   gsrc + r*16 + i*4096
    const float* gsrc = sim + (((size_t)(pair0 + u)) << 8) + (q << 2);
    // LDS write base (floats); + i*256 per instr
    float* wbase = lds + ((u * 4 + (q ^ ((t >> 3) & 3))) << 2);

    float R[18], C[16], dr[16];
    float4 A[4], B[4];

#define LOADN(buf, r)                                                              \
    _Pragma("unroll")                                                              \
    for (int i = 0; i < 4; ++i)                                                    \
        buf[i] = *reinterpret_cast<const float4*>(gsrc + (r) * 16 + i * 4096);

#define WRITEC(buf)                                                                \
    _Pragma("unroll")                                                              \
    for (int i = 0; i < 4; ++i) {                                                  \
        float4 w;                                                                  \
        w.x = 1.0f - buf[i].x; w.y = 1.0f - buf[i].y;                              \
        w.z = 1.0f - buf[i].z; w.w = 1.0f - buf[i].w;                              \
        *reinterpret_cast<float4*>(wbase + i * 256) = w;                           \
    }

#define READR()                                                                    \
    _Pragma("unroll")                                                              \
    for (int j = 0; j < 4; ++j) {                                                  \
        float4 v = *reinterpret_cast<const float4*>(                               \
            lds + t * 16 + ((j ^ ((t >> 1) & 3)) << 2));                           \
        dr[j * 4 + 0] = v.x; dr[j * 4 + 1] = v.y;                                  \
        dr[j * 4 + 2] = v.z; dr[j * 4 + 3] = v.w;                                  \
    }

    // ---- row 0: load, prefetch row 1, stage, cumsum init + DP2 col m=1 ----
    LOADN(A, 0);
    LOADN(B, 1);          // in flight during row 0 staging+compute
    WRITEC(A);            // compiler waits vmcnt(4) here (A needed, B flying)
    READR();
    R[0] = 0.0f;
#pragma unroll
    for (int m = 1; m <= 16; ++m) R[m] = R[m - 1] + dr[m - 1];
    R[17] = R[16];
    C[0] = dr[0];
#pragma unroll
    for (int l = 1; l < 16; ++l)
        C[l] = dr[l] + softmin3(0.0f, 0.0f, C[l - 1]);

    // ---- rows 1..15: alternate A/B, prefetch r+1 before staging r ----
#pragma unroll
    for (int r = 1; r < 16; ++r) {
        if (r & 1) {
            if (r < 15) LOADN(A, r + 1);
            WRITEC(B);
        } else {
            if (r < 15) LOADN(B, r + 1);
            WRITEC(A);
        }
        READR();
        dp_row(R, dr);
        dp_col(C, dr);
    }

    // ---- DP2 final column m = 17 (d = 0, boundary) ----
    {
        float diag2 = C[0];
#pragma unroll
        for (int l = 1; l < 16; ++l) {
            float o = C[l];
            C[l] = softmin3(diag2, o, C[l - 1]);
            diag2 = o;
        }
    }

    out[pair0 + t] = -0.5f * (R[17] + C[15]);
#undef LOADN
#undef WRITEC
#undef READR
}

extern "C" void kernel_launch(void* const* d_in, const int* in_sizes, int n_in,
                              void* d_out, int out_size, void* d_ws, size_t ws_size,
                              hipStream_t stream) {
    const float* sim = (const float*)d_in[0];
    float* out = (float*)d_out;
    int npairs = in_sizes[0] >> 8;          // 262144
    int grid = npairs >> 8;                 // 256 pairs per block
    otam_fused_kernel<<<grid, 256, 0, stream>>>(sim, out);
}

// Round 7
// 53.010 us; speedup vs baseline: 1.2562x; 1.2562x over previous
//
#include <hip/hip_runtime.h>

// OTAM cumulative-distance matching, fused forward+transposed DP, one pass.
// similarity: [2048, 128, 16, 16] f32 ; out: [2048, 128] f32
//
// v7 = v4 (proven 54.6us) + one change: next chunk's global loads are issued
// between the two row-computes of the current chunk (same ld[] registers,
// last use was WRITEC at iteration start). Compiler-tracked vmcnt => the
// stage of chunk c+1 waits on loads that have had ~1 row of compute (x4
// waves/SIMD of wall time) to land, instead of stalling cold.
// Rolled main loop (R6 lesson: full unroll blows L1I).

#define K2   14.4269504088896340736f   // 1/(lambda*ln2), lambda = 0.1
#define LL2  0.069314718055994530942f  // lambda*ln(2)

// softmin(a,b) = min - L*ln2*log2(1 + exp2(-|a-b|/(L*ln2)))
__device__ __forceinline__ float softmin2(float a, float b) {
    float mn = fminf(a, b);
    float t  = __builtin_amdgcn_exp2f(-K2 * fabsf(a - b));
    return mn - LL2 * __builtin_amdgcn_logf(1.0f + t);   // logf = v_log_f32 = log2
}

__device__ __forceinline__ float softmin3(float a, float b, float c) {
    float mn = fminf(fminf(a, b), c);   // v_min3_f32
    float s = __builtin_amdgcn_exp2f(-K2 * (a - mn))
            + __builtin_amdgcn_exp2f(-K2 * (b - mn))
            + __builtin_amdgcn_exp2f(-K2 * (c - mn));
    return mn - LL2 * __builtin_amdgcn_logf(s);
}

// DP1 (row-major over D): one row step, in-place with diagonal carry.
__device__ __forceinline__ void dp_row(float* R, const float* dr) {
    float diag = R[0];              // cum1[r-1, 0] = 0
    float oldR = R[1];
    R[1] = dr[0] + softmin3(diag, R[0], oldR);   // m = 1 boundary
    diag = oldR;
#pragma unroll
    for (int m = 2; m <= 16; ++m) {
        float o = R[m];
        R[m] = dr[m - 1] + softmin2(diag, R[m - 1]);
        diag = o;
    }
    R[17] = softmin3(diag, R[16], R[17]);        // m = 17 pad, d = 0, boundary
}

// DP2 (the DP on D^T, advanced column-major): one interior column step.
__device__ __forceinline__ void dp_col(float* C, const float* dr) {
    float diag2 = C[0];             // cum2[0, m-1]
    C[0] = C[0] + dr[0];            // row 0 of DP2 is a plain cumsum
#pragma unroll
    for (int l = 1; l < 16; ++l) {
        float o = C[l];
        C[l] = dr[l] + softmin2(diag2, o);
        diag2 = o;
    }
}

__global__ __launch_bounds__(256, 2)
void otam_fused_kernel(const float* __restrict__ sim, float* __restrict__ out) {
    const int t  = threadIdx.x & 63;
    const int wv = threadIdx.x >> 6;
    const int pair0 = blockIdx.x * 256 + wv * 64;

    __shared__ float lds_all[4 * 2048];              // 32 KB: 4 waves x 8 KB
    float* lds = lds_all + (wv << 11);               // wave-private -> no barriers

    const int u = t >> 3;                            // 0..7
    const int c = t & 7;                             // 0..7

    // global: instr i of chunk cc -> pair (pair0 + i*8 + u), bytes cc*128 + c*16
    const float* gbase = sim + (((size_t)(pair0 + u)) << 8) + (c << 2);
    // LDS write base (floats): slot (u*8 + (c^u)) ; + i*256 floats per instr
    float* wbase = lds + ((u * 8 + (c ^ u)) << 2);

    float R[18], C[16], dr[16];
    float4 ld[8];

#define LOADN(cc)                                                                  \
    _Pragma("unroll")                                                              \
    for (int i = 0; i < 8; ++i)                                                    \
        ld[i] = *reinterpret_cast<const float4*>(gbase + i * 2048 + (cc) * 32);

#define WRITEC()                                                                   \
    _Pragma("unroll")                                                              \
    for (int i = 0; i < 8; ++i) {                                                  \
        float4 w;                                                                  \
        w.x = 1.0f - ld[i].x; w.y = 1.0f - ld[i].y;                                \
        w.z = 1.0f - ld[i].z; w.w = 1.0f - ld[i].w;                                \
        *reinterpret_cast<float4*>(wbase + i * 256) = w;                           \
    }

#define READR(rr)                                                                  \
    _Pragma("unroll")                                                              \
    for (int k = 0; k < 4; ++k) {                                                  \
        float4 v = *reinterpret_cast<const float4*>(                               \
            lds + t * 32 + ((((rr) * 4 + k) ^ c) << 2));                           \
        dr[k * 4 + 0] = v.x; dr[k * 4 + 1] = v.y;                                  \
        dr[k * 4 + 2] = v.z; dr[k * 4 + 3] = v.w;                                  \
    }

    // ---------- chunk 0 (rows 0,1) ----------
    LOADN(0);
    WRITEC();

    // row 0: DP1 row 0 = cumsum; DP2 column m=1 (boundary)
    READR(0);
    R[0] = 0.0f;
#pragma unroll
    for (int m = 1; m <= 16; ++m) R[m] = R[m - 1] + dr[m - 1];
    R[17] = R[16];
    C[0] = dr[0];
#pragma unroll
    for (int l = 1; l < 16; ++l)
        C[l] = dr[l] + softmin3(0.0f, 0.0f, C[l - 1]);

    LOADN(1);            // chunk 1 in flight during row 1 compute

    // row 1
    READR(1);
    dp_row(R, dr);
    dp_col(C, dr);

    // ---------- chunks 1..7 (rows 2..15), rolled loop ----------
    for (int cc = 1; cc < 8; ++cc) {
        WRITEC();        // waits this chunk's loads (issued one row-compute ago)
        READR(0);
        dp_row(R, dr);
        dp_col(C, dr);
        if (cc < 7) LOADN(cc + 1);   // next chunk flies during second row
        READR(1);
        dp_row(R, dr);
        dp_col(C, dr);
    }

    // ---------- DP2 final column m = 17 (d = 0, boundary) ----------
    {
        float diag2 = C[0];
#pragma unroll
        for (int l = 1; l < 16; ++l) {
            float o = C[l];
            C[l] = softmin3(diag2, o, C[l - 1]);
            diag2 = o;
        }
    }

    out[pair0 + t] = -0.5f * (R[17] + C[15]);
#undef LOADN
#undef WRITEC
#undef READR
}

extern "C" void kernel_launch(void* const* d_in, const int* in_sizes, int n_in,
                              void* d_out, int out_size, void* d_ws, size_t ws_size,
                              hipStream_t stream) {
    const float* sim = (const float*)d_in[0];
    float* out = (float*)d_out;
    int npairs = in_sizes[0] >> 8;          // 262144
    int grid = npairs >> 8;                 // 256 pairs per block
    otam_fused_kernel<<<grid, 256, 0, stream>>>(sim, out);
}